// Round 8
// baseline (2908.128 us; speedup 1.0000x reference)
//
#include <hip/hip_runtime.h>
#include <hip/hip_bf16.h>
#include <math.h>

#define BB 2
#define SS 4096
#define DMM 1024
#define HH 16
#define DKK 64
#define RR 4
#define NROT 32
#define NC 64

// ---------------- f32 GEMM: C = A @ W^T + bias ----------------
// MODE 1 models OpenBLAS sgemm (FMA micro-kernel) with GEMM_Q in [512,1023]:
//   kc chunks [512,512]; per element each chunk is a sequential ascending-k
//   FMA chain into one accumulator; C = r0 then C += r1 (s0+s1); bias after.
// MODE 0: plain sequential-k FMA chain (smooth paths: V proj, final Wo).
// mode arg: 0 -> dst [B,H,S,DK] (proj), 1 -> dst [M,1024] (final out)
template<int MODE>
__global__ __launch_bounds__(256)
void gemm_xwt(const float* __restrict__ A, const float* __restrict__ W,
              const float* __restrict__ bias, float* __restrict__ dst, int mode)
{
    #pragma clang fp contract(off)
    __shared__ __align__(16) float AsT[16][68];
    __shared__ __align__(16) float WsT[16][68];
    const int K = DMM;
    const int t = threadIdx.x;
    const int bx = blockIdx.x, by = blockIdx.y;
    const int tx = t & 15, ty = t >> 4;
    const int i0 = ty * 4, j0 = tx * 4;
    const int rl = t >> 2, kq = (t & 3) * 4;
    const float* Ap = A + ((size_t)(by * 64 + rl)) * K + kq;
    const float* Wp = W + ((size_t)(bx * 64 + rl)) * K + kq;
    float acc0[4][4] = {}, acc1[4][4] = {};
    for (int k0 = 0; k0 < K; k0 += 16) {
        const float4 av = *(const float4*)(Ap + k0);
        const float4 wv = *(const float4*)(Wp + k0);
        __syncthreads();
        AsT[kq+0][rl] = av.x; AsT[kq+1][rl] = av.y; AsT[kq+2][rl] = av.z; AsT[kq+3][rl] = av.w;
        WsT[kq+0][rl] = wv.x; WsT[kq+1][rl] = wv.y; WsT[kq+2][rl] = wv.z; WsT[kq+3][rl] = wv.w;
        __syncthreads();
        float (*ac)[4] = (MODE == 1 && k0 >= 512) ? acc1 : acc0;
        #pragma unroll
        for (int kk = 0; kk < 16; kk++) {
            const float4 a = *(const float4*)&AsT[kk][i0];
            const float4 w = *(const float4*)&WsT[kk][j0];
            const float a_[4] = {a.x, a.y, a.z, a.w};
            const float w_[4] = {w.x, w.y, w.z, w.w};
            #pragma unroll
            for (int ii = 0; ii < 4; ii++)
                #pragma unroll
                for (int jj = 0; jj < 4; jj++)
                    ac[ii][jj] = __builtin_fmaf(a_[ii], w_[jj], ac[ii][jj]);
        }
    }
    float cf[4][4];
    #pragma unroll
    for (int ii = 0; ii < 4; ii++)
        #pragma unroll
        for (int jj = 0; jj < 4; jj++)
            cf[ii][jj] = (MODE == 1) ? (acc0[ii][jj] + acc1[ii][jj]) : acc0[ii][jj];
    const float4 bv = *(const float4*)(bias + bx * 64 + j0);
    const int m0 = by * 64 + i0;
    if (mode == 0) {
        const int h = bx;
        #pragma unroll
        for (int ii = 0; ii < 4; ii++) {
            const int m = m0 + ii, b = m >> 12, s = m & (SS - 1);
            const float4 o = make_float4(cf[ii][0]+bv.x, cf[ii][1]+bv.y,
                                         cf[ii][2]+bv.z, cf[ii][3]+bv.w);
            *(float4*)(dst + (((size_t)b * HH + h) * SS + s) * DKK + j0) = o;
        }
    } else {
        #pragma unroll
        for (int ii = 0; ii < 4; ii++) {
            const float4 o = make_float4(cf[ii][0]+bv.x, cf[ii][1]+bv.y,
                                         cf[ii][2]+bv.z, cf[ii][3]+bv.w);
            *(float4*)(dst + (size_t)(m0 + ii) * DMM + bx * 64 + j0) = o;
        }
    }
}

// ---------------- LSH bucketing ----------------
// rq[n] = sum_d q[d]*rot[r,d,n], d ascending, SEPARATE mul+add (no FMA) --
// matches numpy einsum's sum-of-products rounding (structurally forced:
// rot is not d-contiguous so no pairwise/SIMD-reduction path exists).
// bucket = first-argmax([rq, -rq]).
__global__ __launch_bounds__(256)
void bucketize(const float* __restrict__ x, const float* __restrict__ rot,
               int* __restrict__ buck)
{
    #pragma clang fp contract(off)
    const int r = blockIdx.z, bh = blockIdx.y;
    const int s = blockIdx.x * 256 + threadIdx.x;
    const float* rp = rot + (size_t)r * DKK * NROT;
    const float* xp = x + ((size_t)bh * SS + s) * DKK;
    float qv[DKK];
    #pragma unroll
    for (int d = 0; d < DKK; d += 4) {
        const float4 v = *(const float4*)(xp + d);
        qv[d] = v.x; qv[d+1] = v.y; qv[d+2] = v.z; qv[d+3] = v.w;
    }
    float rq[NROT];
    #pragma unroll
    for (int n = 0; n < NROT; n++) rq[n] = 0.f;
    for (int d = 0; d < DKK; d++) {
        const float qd = qv[d];
        const float4* rv4 = (const float4*)(rp + d * NROT);
        #pragma unroll
        for (int n4 = 0; n4 < 8; n4++) {
            const float4 rv = rv4[n4];
            const float p0 = qd * rv.x;
            const float p1 = qd * rv.y;
            const float p2 = qd * rv.z;
            const float p3 = qd * rv.w;
            rq[n4*4+0] = rq[n4*4+0] + p0;
            rq[n4*4+1] = rq[n4*4+1] + p1;
            rq[n4*4+2] = rq[n4*4+2] + p2;
            rq[n4*4+3] = rq[n4*4+3] + p3;
        }
    }
    float best = rq[0]; int bi = 0;
    #pragma unroll
    for (int n = 1; n < NROT; n++) if (rq[n] > best) { best = rq[n]; bi = n; }
    #pragma unroll
    for (int n = 0; n < NROT; n++) { const float v = -rq[n]; if (v > best) { best = v; bi = NROT + n; } }
    buck[((size_t)r * BB * HH + bh) * SS + s] = bi;
}

// ---------------- stable counting sort by bucket ----------------
__global__ __launch_bounds__(64)
void bucket_sort(const int* __restrict__ buck, int* __restrict__ idx)
{
    const int seg = blockIdx.x;
    const int* bp = buck + (size_t)seg * SS;
    int* ip = idx + (size_t)seg * SS;
    __shared__ int hist[64][65];
    const int c = threadIdx.x;
    for (int j = 0; j < 64; j++) hist[c][j] = 0;
    __syncthreads();
    for (int e = 0; e < 64; e++) hist[c][bp[c * 64 + e]]++;
    __syncthreads();
    int run = 0;
    for (int cc = 0; cc < 64; cc++) { const int tv = hist[cc][c]; hist[cc][c] = run; run += tv; }
    int x = run;
    for (int off = 1; off < 64; off <<= 1) { const int v = __shfl_up(x, off); if (c >= off) x += v; }
    const int base = x - run;
    for (int cc = 0; cc < 64; cc++) hist[cc][c] += base;
    __syncthreads();
    for (int e = 0; e < 64; e++) {
        const int s = c * 64 + e;
        const int bk = bp[s];
        ip[hist[c][bk]++] = s;
    }
}

// ---------------- chunked LSH attention ----------------
__global__ __launch_bounds__(256)
void lsh_attn(const float* __restrict__ qg, const float* __restrict__ kg,
              const float* __restrict__ vg, const int* __restrict__ qbuck,
              const int* __restrict__ kbuck, const int* __restrict__ qidx,
              const int* __restrict__ kidx, float* __restrict__ oacc)
{
    const int n = blockIdx.x, bh = blockIdx.y, r = blockIdx.z;
    const int b = bh >> 4, h = bh & 15;
    const size_t seg = ((size_t)r * BB * HH + bh) * SS;
    const float* qbase = qg + (size_t)bh * SS * DKK;
    const float* kbase = kg + (size_t)bh * SS * DKK;
    const float* vbase = vg + (size_t)bh * SS * DKK;

    __shared__ __align__(16) float qs[64][68];
    __shared__ __align__(16) float ke[128][68];
    __shared__ __align__(16) float ve[128][68];
    __shared__ __align__(16) float ps[64][132];
    __shared__ int qbv[64], kbv[128], qsrc[64];

    const int t = threadIdx.x;
    {
        const int row = t >> 2, q4 = (t & 3) * 16;
        const int sq = qidx[seg + n * 64 + row];
        if ((t & 3) == 0) { qsrc[row] = sq; qbv[row] = qbuck[seg + sq]; }
        const float* src = qbase + (size_t)sq * DKK + q4;
        #pragma unroll
        for (int x = 0; x < 16; x += 4)
            *(float4*)&qs[row][q4 + x] = *(const float4*)(src + x);
    }
    #pragma unroll
    for (int pass = 0; pass < 2; pass++) {
        const int row = pass * 64 + (t >> 2), q4 = (t & 3) * 16;
        const int cn = (pass == 0) ? ((n + NC - 1) & (NC - 1)) : n;
        const int sk = kidx[seg + cn * 64 + (row & 63)];
        if ((t & 3) == 0) kbv[row] = kbuck[seg + sk];
        const float* ksrc = kbase + (size_t)sk * DKK + q4;
        const float* vsrc = vbase + (size_t)sk * DKK + q4;
        #pragma unroll
        for (int x = 0; x < 16; x += 4) {
            *(float4*)&ke[row][q4 + x] = *(const float4*)(ksrc + x);
            *(float4*)&ve[row][q4 + x] = *(const float4*)(vsrc + x);
        }
    }
    __syncthreads();

    const int ig = t >> 3, jg = t & 7;
    const int r0 = ig * 2;
    float sc0[16], sc1[16];
    #pragma unroll
    for (int jj = 0; jj < 16; jj++) { sc0[jj] = 0.f; sc1[jj] = 0.f; }
    #pragma unroll
    for (int d4 = 0; d4 < DKK; d4 += 4) {
        const float4 a0 = *(const float4*)&qs[r0][d4];
        const float4 a1 = *(const float4*)&qs[r0 + 1][d4];
        #pragma unroll
        for (int jj = 0; jj < 16; jj++) {
            const float4 kv = *(const float4*)&ke[jj * 8 + jg][d4];
            sc0[jj] += a0.x*kv.x + a0.y*kv.y + a0.z*kv.z + a0.w*kv.w;
            sc1[jj] += a1.x*kv.x + a1.y*kv.y + a1.z*kv.z + a1.w*kv.w;
        }
    }
    const int qb0 = qbv[r0], qb1 = qbv[r0 + 1];
    float m0 = -INFINITY, m1 = -INFINITY;
    #pragma unroll
    for (int jj = 0; jj < 16; jj++) {
        const int kb = kbv[jj * 8 + jg];
        float s0 = sc0[jj] * 0.125f; if (kb != qb0) s0 = -1e9f;
        float s1 = sc1[jj] * 0.125f; if (kb != qb1) s1 = -1e9f;
        sc0[jj] = s0; sc1[jj] = s1;
        m0 = fmaxf(m0, s0); m1 = fmaxf(m1, s1);
    }
    m0 = fmaxf(m0, __shfl_xor(m0, 1)); m1 = fmaxf(m1, __shfl_xor(m1, 1));
    m0 = fmaxf(m0, __shfl_xor(m0, 2)); m1 = fmaxf(m1, __shfl_xor(m1, 2));
    m0 = fmaxf(m0, __shfl_xor(m0, 4)); m1 = fmaxf(m1, __shfl_xor(m1, 4));
    float sum0 = 0.f, sum1 = 0.f;
    #pragma unroll
    for (int jj = 0; jj < 16; jj++) {
        const float e0 = __expf(sc0[jj] - m0);
        const float e1 = __expf(sc1[jj] - m1);
        sc0[jj] = e0; sc1[jj] = e1;
        sum0 += e0; sum1 += e1;
    }
    sum0 += __shfl_xor(sum0, 1); sum1 += __shfl_xor(sum1, 1);
    sum0 += __shfl_xor(sum0, 2); sum1 += __shfl_xor(sum1, 2);
    sum0 += __shfl_xor(sum0, 4); sum1 += __shfl_xor(sum1, 4);
    const float inv0 = 1.f / sum0, inv1 = 1.f / sum1;
    #pragma unroll
    for (int jj = 0; jj < 16; jj++) {
        const int j = jj * 8 + jg;
        ps[r0][j]     = sc0[jj] * inv0;
        ps[r0 + 1][j] = sc1[jj] * inv1;
    }
    __syncthreads();

    const int dg = t & 7;
    float a0[8] = {0,0,0,0,0,0,0,0}, a1[8] = {0,0,0,0,0,0,0,0};
    #pragma unroll
    for (int jb = 0; jb < 32; jb++) {
        const float4 p0 = *(const float4*)&ps[r0][jb * 4];
        const float4 p1 = *(const float4*)&ps[r0 + 1][jb * 4];
        const float pj0[4] = {p0.x, p0.y, p0.z, p0.w};
        const float pj1[4] = {p1.x, p1.y, p1.z, p1.w};
        #pragma unroll
        for (int jx = 0; jx < 4; jx++) {
            const int j = jb * 4 + jx;
            const float4 v0 = *(const float4*)&ve[j][dg * 8];
            const float4 v1 = *(const float4*)&ve[j][dg * 8 + 4];
            a0[0] += pj0[jx]*v0.x; a0[1] += pj0[jx]*v0.y; a0[2] += pj0[jx]*v0.z; a0[3] += pj0[jx]*v0.w;
            a0[4] += pj0[jx]*v1.x; a0[5] += pj0[jx]*v1.y; a0[6] += pj0[jx]*v1.z; a0[7] += pj0[jx]*v1.w;
            a1[0] += pj1[jx]*v0.x; a1[1] += pj1[jx]*v0.y; a1[2] += pj1[jx]*v0.z; a1[3] += pj1[jx]*v0.w;
            a1[4] += pj1[jx]*v1.x; a1[5] += pj1[jx]*v1.y; a1[6] += pj1[jx]*v1.z; a1[7] += pj1[jx]*v1.w;
        }
    }
    {
        const int s0_ = qsrc[r0], s1_ = qsrc[r0 + 1];
        float* d0 = oacc + ((size_t)b * SS + s0_) * DMM + h * DKK + dg * 8;
        float* d1 = oacc + ((size_t)b * SS + s1_) * DMM + h * DKK + dg * 8;
        #pragma unroll
        for (int x = 0; x < 8; x++) {
            atomicAdd(d0 + x, a0[x] * 0.25f);
            atomicAdd(d1 + x, a1[x] * 0.25f);
        }
    }
}

extern "C" void kernel_launch(void* const* d_in, const int* in_sizes, int n_in,
                              void* d_out, int out_size, void* d_ws, size_t ws_size,
                              hipStream_t stream) {
    const float* query = (const float*)d_in[0];
    const float* key   = (const float*)d_in[1];
    const float* value = (const float*)d_in[2];
    const float* Wq = (const float*)d_in[3];
    const float* bq = (const float*)d_in[4];
    const float* Wk = (const float*)d_in[5];
    const float* bk = (const float*)d_in[6];
    const float* Wv = (const float*)d_in[7];
    const float* bv = (const float*)d_in[8];
    const float* Wo = (const float*)d_in[9];
    const float* bo = (const float*)d_in[10];
    const float* rot = (const float*)d_in[11];
    float* out = (float*)d_out;

    const size_t PROJ = (size_t)BB * HH * SS * DKK;
    const size_t OACC = (size_t)BB * SS * DMM;
    const size_t BKN  = (size_t)RR * BB * HH * SS;

    float* qp   = (float*)d_ws;
    float* kp   = qp + PROJ;
    float* vp   = kp + PROJ;
    float* oacc = vp + PROJ;
    int* qbk = (int*)(oacc + OACC);
    int* kbk = qbk + BKN;
    int* qix = kbk + BKN;
    int* kix = qix + BKN;

    hipMemsetAsync(oacc, 0, OACC * sizeof(float), stream);

    dim3 gg(DMM / 64, (BB * SS) / 64);
    gemm_xwt<1><<<gg, 256, 0, stream>>>(query, Wq, bq, qp, 0);
    gemm_xwt<1><<<gg, 256, 0, stream>>>(key,   Wk, bk, kp, 0);
    gemm_xwt<0><<<gg, 256, 0, stream>>>(value, Wv, bv, vp, 0);

    dim3 gb(SS / 256, BB * HH, RR);
    bucketize<<<gb, 256, 0, stream>>>(qp, rot, qbk);
    bucketize<<<gb, 256, 0, stream>>>(kp, rot, kbk);

    bucket_sort<<<RR * BB * HH, 64, 0, stream>>>(qbk, qix);
    bucket_sort<<<RR * BB * HH, 64, 0, stream>>>(kbk, kix);

    dim3 ga(NC, BB * HH, RR);
    lsh_attn<<<ga, 256, 0, stream>>>(qp, kp, vp, qbk, kbk, qix, kix, oacc);

    gemm_xwt<0><<<gg, 256, 0, stream>>>(oacc, Wo, bo, out, 1);
}

// Round 9
// 2512.288 us; speedup vs baseline: 1.1576x; 1.1576x over previous
//
#include <hip/hip_runtime.h>
#include <hip/hip_bf16.h>
#include <math.h>

#define BB 2
#define SS 4096
#define DMM 1024
#define HH 16
#define DKK 64
#define RR 4
#define NROT 32
#define NC 64

// ---------------- f32 GEMM: C = A @ W^T + bias ----------------
// MODE 1 models OpenBLAS sgemm (FMA micro-kernel) with GEMM_Q in [512,1023]:
//   kc chunks [512,512]; per element each chunk is a sequential ascending-k
//   FMA chain into one accumulator; C = r0 then C += r1 (s0+s1); bias after.
//   *** BIT-EXACT vs the np reference -- DO NOT TOUCH the arithmetic. ***
// MODE 0: plain sequential-k FMA chain (smooth paths: V proj, final Wo).
// mode arg: 0 -> dst [B,H,S,DK] (proj), 1 -> dst [M,1024] (final out)
template<int MODE>
__global__ __launch_bounds__(256)
void gemm_xwt(const float* __restrict__ A, const float* __restrict__ W,
              const float* __restrict__ bias, float* __restrict__ dst, int mode)
{
    #pragma clang fp contract(off)
    __shared__ __align__(16) float AsT[16][68];
    __shared__ __align__(16) float WsT[16][68];
    const int K = DMM;
    const int t = threadIdx.x;
    const int bx = blockIdx.x, by = blockIdx.y;
    const int tx = t & 15, ty = t >> 4;
    const int i0 = ty * 4, j0 = tx * 4;
    const int rl = t >> 2, kq = (t & 3) * 4;
    const float* Ap = A + ((size_t)(by * 64 + rl)) * K + kq;
    const float* Wp = W + ((size_t)(bx * 64 + rl)) * K + kq;
    float acc0[4][4] = {}, acc1[4][4] = {};
    for (int k0 = 0; k0 < K; k0 += 16) {
        const float4 av = *(const float4*)(Ap + k0);
        const float4 wv = *(const float4*)(Wp + k0);
        __syncthreads();
        AsT[kq+0][rl] = av.x; AsT[kq+1][rl] = av.y; AsT[kq+2][rl] = av.z; AsT[kq+3][rl] = av.w;
        WsT[kq+0][rl] = wv.x; WsT[kq+1][rl] = wv.y; WsT[kq+2][rl] = wv.z; WsT[kq+3][rl] = wv.w;
        __syncthreads();
        float (*ac)[4] = (MODE == 1 && k0 >= 512) ? acc1 : acc0;
        #pragma unroll
        for (int kk = 0; kk < 16; kk++) {
            const float4 a = *(const float4*)&AsT[kk][i0];
            const float4 w = *(const float4*)&WsT[kk][j0];
            const float a_[4] = {a.x, a.y, a.z, a.w};
            const float w_[4] = {w.x, w.y, w.z, w.w};
            #pragma unroll
            for (int ii = 0; ii < 4; ii++)
                #pragma unroll
                for (int jj = 0; jj < 4; jj++)
                    ac[ii][jj] = __builtin_fmaf(a_[ii], w_[jj], ac[ii][jj]);
        }
    }
    float cf[4][4];
    #pragma unroll
    for (int ii = 0; ii < 4; ii++)
        #pragma unroll
        for (int jj = 0; jj < 4; jj++)
            cf[ii][jj] = (MODE == 1) ? (acc0[ii][jj] + acc1[ii][jj]) : acc0[ii][jj];
    const float4 bv = *(const float4*)(bias + bx * 64 + j0);
    const int m0 = by * 64 + i0;
    if (mode == 0) {
        const int h = bx;
        #pragma unroll
        for (int ii = 0; ii < 4; ii++) {
            const int m = m0 + ii, b = m >> 12, s = m & (SS - 1);
            const float4 o = make_float4(cf[ii][0]+bv.x, cf[ii][1]+bv.y,
                                         cf[ii][2]+bv.z, cf[ii][3]+bv.w);
            *(float4*)(dst + (((size_t)b * HH + h) * SS + s) * DKK + j0) = o;
        }
    } else {
        #pragma unroll
        for (int ii = 0; ii < 4; ii++) {
            const float4 o = make_float4(cf[ii][0]+bv.x, cf[ii][1]+bv.y,
                                         cf[ii][2]+bv.z, cf[ii][3]+bv.w);
            *(float4*)(dst + (size_t)(m0 + ii) * DMM + bx * 64 + j0) = o;
        }
    }
}

// ---------------- LSH bucketing ----------------
// *** BIT-EXACT vs np einsum (d-ascending separate mul+add) -- DO NOT TOUCH ***
__global__ __launch_bounds__(256)
void bucketize(const float* __restrict__ x, const float* __restrict__ rot,
               int* __restrict__ buck)
{
    #pragma clang fp contract(off)
    const int r = blockIdx.z, bh = blockIdx.y;
    const int s = blockIdx.x * 256 + threadIdx.x;
    const float* rp = rot + (size_t)r * DKK * NROT;
    const float* xp = x + ((size_t)bh * SS + s) * DKK;
    float qv[DKK];
    #pragma unroll
    for (int d = 0; d < DKK; d += 4) {
        const float4 v = *(const float4*)(xp + d);
        qv[d] = v.x; qv[d+1] = v.y; qv[d+2] = v.z; qv[d+3] = v.w;
    }
    float rq[NROT];
    #pragma unroll
    for (int n = 0; n < NROT; n++) rq[n] = 0.f;
    for (int d = 0; d < DKK; d++) {
        const float qd = qv[d];
        const float4* rv4 = (const float4*)(rp + d * NROT);
        #pragma unroll
        for (int n4 = 0; n4 < 8; n4++) {
            const float4 rv = rv4[n4];
            const float p0 = qd * rv.x;
            const float p1 = qd * rv.y;
            const float p2 = qd * rv.z;
            const float p3 = qd * rv.w;
            rq[n4*4+0] = rq[n4*4+0] + p0;
            rq[n4*4+1] = rq[n4*4+1] + p1;
            rq[n4*4+2] = rq[n4*4+2] + p2;
            rq[n4*4+3] = rq[n4*4+3] + p3;
        }
    }
    float best = rq[0]; int bi = 0;
    #pragma unroll
    for (int n = 1; n < NROT; n++) if (rq[n] > best) { best = rq[n]; bi = n; }
    #pragma unroll
    for (int n = 0; n < NROT; n++) { const float v = -rq[n]; if (v > best) { best = v; bi = NROT + n; } }
    buck[((size_t)r * BB * HH + bh) * SS + s] = bi;
}

// ---------------- stable counting sort by bucket ----------------
__global__ __launch_bounds__(64)
void bucket_sort(const int* __restrict__ buck, int* __restrict__ idx)
{
    const int seg = blockIdx.x;
    const int* bp = buck + (size_t)seg * SS;
    int* ip = idx + (size_t)seg * SS;
    __shared__ int hist[64][65];
    const int c = threadIdx.x;
    for (int j = 0; j < 64; j++) hist[c][j] = 0;
    __syncthreads();
    for (int e = 0; e < 64; e++) hist[c][bp[c * 64 + e]]++;
    __syncthreads();
    int run = 0;
    for (int cc = 0; cc < 64; cc++) { const int tv = hist[cc][c]; hist[cc][c] = run; run += tv; }
    int x = run;
    for (int off = 1; off < 64; off <<= 1) { const int v = __shfl_up(x, off); if (c >= off) x += v; }
    const int base = x - run;
    for (int cc = 0; cc < 64; cc++) hist[cc][c] += base;
    __syncthreads();
    for (int e = 0; e < 64; e++) {
        const int s = c * 64 + e;
        const int bk = bp[s];
        ip[hist[c][bk]++] = s;
    }
}

// ---------------- chunked LSH attention (LDS-slim: 53.7 KB -> 3 blocks/CU) ---
// K and V time-share one [128][68] buffer; P stays in registers and is
// distributed across the 8-thread row-group via __shfl in the PV phase.
__global__ __launch_bounds__(256)
void lsh_attn(const float* __restrict__ qg, const float* __restrict__ kg,
              const float* __restrict__ vg, const int* __restrict__ qbuck,
              const int* __restrict__ kbuck, const int* __restrict__ qidx,
              const int* __restrict__ kidx, float* __restrict__ oacc)
{
    const int n = blockIdx.x, bh = blockIdx.y, r = blockIdx.z;
    const int b = bh >> 4, h = bh & 15;
    const size_t seg = ((size_t)r * BB * HH + bh) * SS;
    const float* qbase = qg + (size_t)bh * SS * DKK;
    const float* kbase = kg + (size_t)bh * SS * DKK;
    const float* vbase = vg + (size_t)bh * SS * DKK;

    __shared__ __align__(16) float qs[64][68];     // 17408 B
    __shared__ __align__(16) float kv[128][68];    // 34816 B (K then V)
    __shared__ int qbv[64], kbv[128], qsrc[64], ksrc[128];   // 1536 B

    const int t = threadIdx.x;
    {   // gather 64 query rows (4 threads/row, 16 floats each)
        const int row = t >> 2, q4 = (t & 3) * 16;
        const int sq = qidx[seg + n * 64 + row];
        if ((t & 3) == 0) { qsrc[row] = sq; qbv[row] = qbuck[seg + sq]; }
        const float* src = qbase + (size_t)sq * DKK + q4;
        #pragma unroll
        for (int x = 0; x < 16; x += 4)
            *(float4*)&qs[row][q4 + x] = *(const float4*)(src + x);
    }
    #pragma unroll
    for (int pass = 0; pass < 2; pass++) {   // K rows: 0..63 prev chunk, 64..127 cur
        const int row = pass * 64 + (t >> 2), q4 = (t & 3) * 16;
        const int cn = (pass == 0) ? ((n + NC - 1) & (NC - 1)) : n;
        const int sk = kidx[seg + cn * 64 + (row & 63)];
        if ((t & 3) == 0) { kbv[row] = kbuck[seg + sk]; ksrc[row] = sk; }
        const float* src = kbase + (size_t)sk * DKK + q4;
        #pragma unroll
        for (int x = 0; x < 16; x += 4)
            *(float4*)&kv[row][q4 + x] = *(const float4*)(src + x);
    }
    __syncthreads();

    // scores: thread (ig,jg) owns rows 2ig,2ig+1 x cols {jj*8+jg}
    const int ig = t >> 3, jg = t & 7;
    const int r0 = ig * 2;
    float sc0[16], sc1[16];
    #pragma unroll
    for (int jj = 0; jj < 16; jj++) { sc0[jj] = 0.f; sc1[jj] = 0.f; }
    #pragma unroll
    for (int d4 = 0; d4 < DKK; d4 += 4) {
        const float4 a0 = *(const float4*)&qs[r0][d4];
        const float4 a1 = *(const float4*)&qs[r0 + 1][d4];
        #pragma unroll
        for (int jj = 0; jj < 16; jj++) {
            const float4 kvv = *(const float4*)&kv[jj * 8 + jg][d4];
            sc0[jj] += a0.x*kvv.x + a0.y*kvv.y + a0.z*kvv.z + a0.w*kvv.w;
            sc1[jj] += a1.x*kvv.x + a1.y*kvv.y + a1.z*kvv.z + a1.w*kvv.w;
        }
    }
    const int qb0 = qbv[r0], qb1 = qbv[r0 + 1];
    float m0 = -INFINITY, m1 = -INFINITY;
    #pragma unroll
    for (int jj = 0; jj < 16; jj++) {
        const int kb = kbv[jj * 8 + jg];
        float s0 = sc0[jj] * 0.125f; if (kb != qb0) s0 = -1e9f;
        float s1 = sc1[jj] * 0.125f; if (kb != qb1) s1 = -1e9f;
        sc0[jj] = s0; sc1[jj] = s1;
        m0 = fmaxf(m0, s0); m1 = fmaxf(m1, s1);
    }
    m0 = fmaxf(m0, __shfl_xor(m0, 1)); m1 = fmaxf(m1, __shfl_xor(m1, 1));
    m0 = fmaxf(m0, __shfl_xor(m0, 2)); m1 = fmaxf(m1, __shfl_xor(m1, 2));
    m0 = fmaxf(m0, __shfl_xor(m0, 4)); m1 = fmaxf(m1, __shfl_xor(m1, 4));
    float sum0 = 0.f, sum1 = 0.f;
    #pragma unroll
    for (int jj = 0; jj < 16; jj++) {
        const float e0 = __expf(sc0[jj] - m0);
        const float e1 = __expf(sc1[jj] - m1);
        sc0[jj] = e0; sc1[jj] = e1;
        sum0 += e0; sum1 += e1;
    }
    sum0 += __shfl_xor(sum0, 1); sum1 += __shfl_xor(sum1, 1);
    sum0 += __shfl_xor(sum0, 2); sum1 += __shfl_xor(sum1, 2);
    sum0 += __shfl_xor(sum0, 4); sum1 += __shfl_xor(sum1, 4);
    const float inv0 = 1.f / sum0, inv1 = 1.f / sum1;
    #pragma unroll
    for (int jj = 0; jj < 16; jj++) { sc0[jj] *= inv0; sc1[jj] *= inv1; }

    __syncthreads();   // all K reads done -> reuse kv for V
    #pragma unroll
    for (int pass = 0; pass < 2; pass++) {
        const int row = pass * 64 + (t >> 2), q4 = (t & 3) * 16;
        const int sk = ksrc[row];
        const float* src = vbase + (size_t)sk * DKK + q4;
        #pragma unroll
        for (int x = 0; x < 16; x += 4)
            *(float4*)&kv[row][q4 + x] = *(const float4*)(src + x);
    }
    __syncthreads();

    // PV: rotate P across the 8-thread row-group; each thread owns d-block jg*8
    const int dg = jg;
    const int laneBase = (t & 63) & ~7;
    float a0[8] = {0,0,0,0,0,0,0,0}, a1[8] = {0,0,0,0,0,0,0,0};
    #pragma unroll
    for (int s = 0; s < 8; s++) {
        const int jsrc = (jg + s) & 7;
        const int srcLane = laneBase | jsrc;
        #pragma unroll
        for (int jj = 0; jj < 16; jj++) {
            const float p0 = __shfl(sc0[jj], srcLane);
            const float p1 = __shfl(sc1[jj], srcLane);
            const int j = jj * 8 + jsrc;
            const float4 v0 = *(const float4*)&kv[j][dg * 8];
            const float4 v1 = *(const float4*)&kv[j][dg * 8 + 4];
            a0[0] += p0*v0.x; a0[1] += p0*v0.y; a0[2] += p0*v0.z; a0[3] += p0*v0.w;
            a0[4] += p0*v1.x; a0[5] += p0*v1.y; a0[6] += p0*v1.z; a0[7] += p0*v1.w;
            a1[0] += p1*v0.x; a1[1] += p1*v0.y; a1[2] += p1*v0.z; a1[3] += p1*v0.w;
            a1[4] += p1*v1.x; a1[5] += p1*v1.y; a1[6] += p1*v1.z; a1[7] += p1*v1.w;
        }
    }
    {   // scatter back to original positions, fold 1/R mean
        const int s0_ = qsrc[r0], s1_ = qsrc[r0 + 1];
        float* d0 = oacc + ((size_t)b * SS + s0_) * DMM + h * DKK + dg * 8;
        float* d1 = oacc + ((size_t)b * SS + s1_) * DMM + h * DKK + dg * 8;
        #pragma unroll
        for (int x = 0; x < 8; x++) {
            atomicAdd(d0 + x, a0[x] * 0.25f);
            atomicAdd(d1 + x, a1[x] * 0.25f);
        }
    }
}

extern "C" void kernel_launch(void* const* d_in, const int* in_sizes, int n_in,
                              void* d_out, int out_size, void* d_ws, size_t ws_size,
                              hipStream_t stream) {
    const float* query = (const float*)d_in[0];
    const float* key   = (const float*)d_in[1];
    const float* value = (const float*)d_in[2];
    const float* Wq = (const float*)d_in[3];
    const float* bq = (const float*)d_in[4];
    const float* Wk = (const float*)d_in[5];
    const float* bk = (const float*)d_in[6];
    const float* Wv = (const float*)d_in[7];
    const float* bv = (const float*)d_in[8];
    const float* Wo = (const float*)d_in[9];
    const float* bo = (const float*)d_in[10];
    const float* rot = (const float*)d_in[11];
    float* out = (float*)d_out;

    const size_t PROJ = (size_t)BB * HH * SS * DKK;
    const size_t OACC = (size_t)BB * SS * DMM;
    const size_t BKN  = (size_t)RR * BB * HH * SS;

    float* qp   = (float*)d_ws;
    float* kp   = qp + PROJ;
    float* vp   = kp + PROJ;
    float* oacc = vp + PROJ;
    int* qbk = (int*)(oacc + OACC);
    int* kbk = qbk + BKN;
    int* qix = kbk + BKN;
    int* kix = qix + BKN;

    hipMemsetAsync(oacc, 0, OACC * sizeof(float), stream);

    dim3 gg(DMM / 64, (BB * SS) / 64);
    gemm_xwt<1><<<gg, 256, 0, stream>>>(query, Wq, bq, qp, 0);
    gemm_xwt<1><<<gg, 256, 0, stream>>>(key,   Wk, bk, kp, 0);
    gemm_xwt<0><<<gg, 256, 0, stream>>>(value, Wv, bv, vp, 0);

    dim3 gb(SS / 256, BB * HH, RR);
    bucketize<<<gb, 256, 0, stream>>>(qp, rot, qbk);
    bucketize<<<gb, 256, 0, stream>>>(kp, rot, kbk);

    bucket_sort<<<RR * BB * HH, 64, 0, stream>>>(qbk, qix);
    bucket_sort<<<RR * BB * HH, 64, 0, stream>>>(kbk, kix);

    dim3 ga(NC, BB * HH, RR);
    lsh_attn<<<ga, 256, 0, stream>>>(qp, kp, vp, qbk, kbk, qix, kix, oacc);

    gemm_xwt<0><<<gg, 256, 0, stream>>>(oacc, Wo, bo, out, 1);
}